// Round 1
// baseline (615.176 us; speedup 1.0000x reference)
//
#include <hip/hip_runtime.h>
#include <math.h>

#define BATCH 32
#define NTOK 577
#define NPATCH 576
#define CDIM 768
#define HEADS 12
#define DHEAD 64
#define W3 2304
#define FT 404
#define JBLK 19   // token blocks per batch (19*32 >= 577)

// ---- workspace layout (float offsets) ----
#define WS_WTIL  24576
#define WS_DBIAS 319488
#define WS_DOTS  319872
#define WS_IND   541440

// ---- output layout (float offsets) ----
#define O_X      0ULL
#define O_INDEX  14180352ULL
#define O_IND    24109056ULL
#define O_CA     24121984ULL
#define O_FT     24140416ULL

// Sentinel for cross-block flags. Flag cells live inside O_INDEX and are
// overwritten with final float index values (bit patterns 0x0000_0000 ..
// 0x4410_0000) at the end of every iteration, so a stale sentinel can never
// survive into the next replay; poison patterns also cannot collide.
#define SENT 0x5EE7F1A6u
#define SPIN_GUARD (1 << 18)   // bounded spin: never hangs

__device__ __forceinline__ unsigned flag_ld_acq(const unsigned* p) {
    return __hip_atomic_load(p, __ATOMIC_ACQUIRE, __HIP_MEMORY_SCOPE_AGENT);
}
__device__ __forceinline__ void flag_st_rel(unsigned* p, unsigned v) {
    __hip_atomic_store(p, v, __ATOMIC_RELEASE, __HIP_MEMORY_SCOPE_AGENT);
}
__device__ __forceinline__ void wait_flags(const unsigned* base, int n, int stride) {
    for (int i = 0; i < n; ++i) {
        const unsigned* p = base + (size_t)i * (size_t)stride;
        int guard = 0;
        while (flag_ld_acq(p) != SENT) {
            __builtin_amdgcn_s_sleep(16);
            if (++guard > SPIN_GUARD) break;   // bail -> wrong answer, not a hang
        }
    }
}

// One persistent kernel: fold -> (gate) -> dots+copy -> (gate) -> topk -> (gate) -> bcast.
// Co-residency: LDS ~40.6 KB -> 3 blocks/CU -> 768 slots >= 608 blocks;
// __launch_bounds__(256,3) forces VGPR <= ~170 so VGPRs never gate below 3 blocks/CU.
__global__ __launch_bounds__(256, 3) void k_mega(
        const float* __restrict__ x, const float* __restrict__ W,
        const float* __restrict__ bq, float* __restrict__ ws,
        float* out, int write_ft)
{
    __shared__ float smem[HEADS * CDIM];      // 36 KB, multi-phase reuse
    __shared__ float db[HEADS];
    __shared__ float mh[HEADS], sh[HEADS];
    __shared__ unsigned vals[NPATCH];
    __shared__ int flags[NPATCH];

    const int b = blockIdx.x, y = blockIdx.y, tid = threadIdx.x;
    float* const wtil  = ws + WS_WTIL;
    float* const dbias = ws + WS_DBIAS;
    float* const dots  = ws + WS_DOTS;
    int*   const indws = (int*)(ws + WS_IND);
    unsigned* const idxU = (unsigned*)(out + O_INDEX);
    // flag cell at (row, c) of batch b's O_INDEX slice; c=2: fold[h], c=1: dots[y], c=0: topk[y]
    #define FCELL(row, c) (idxU + (((size_t)b * FT + (size_t)(row)) * CDIM + (c)))

    // ---------------- Phase A: fold (blocks y < 12 compute head h=y) ----------------
    if (y < HEADS) {
        const int h = y;
        float* const x0s = smem;               // 768
        float* const red = smem + CDIM;        // 256
        float* const qs  = smem + CDIM + 256;  // 64
        if (tid < CDIM / 4)
            ((float4*)x0s)[tid] = ((const float4*)(x + (size_t)b * NTOK * CDIM))[tid];
        __syncthreads();
        {
            const int d = tid & 63, seg = tid >> 6;
            const float* Wq = W + (size_t)(h * DHEAD + d);
            float acc = 0.f;
            const int c0 = seg * 192;
            #pragma unroll 8
            for (int c = c0; c < c0 + 192; c++)
                acc += x0s[c] * Wq[(size_t)c * W3];
            red[tid] = acc;
        }
        __syncthreads();
        if (tid < DHEAD) {
            float q = red[tid] + red[tid + 64] + red[tid + 128] + red[tid + 192]
                    + bq[h * DHEAD + tid];
            qs[tid] = q;
            float t = q * bq[CDIM + h * DHEAD + tid];
            #pragma unroll
            for (int off = 32; off; off >>= 1) t += __shfl_down(t, off);
            if (tid == 0) dbias[b * HEADS + h] = t;
        }
        __syncthreads();
        for (int c = tid; c < CDIM; c += 256) {
            const float* wr = W + (size_t)c * W3 + CDIM + h * DHEAD;
            float acc = 0.f;
            #pragma unroll
            for (int d = 0; d < DHEAD; d += 4) {
                float4 a = *reinterpret_cast<const float4*>(wr + d);
                acc += a.x * qs[d] + a.y * qs[d + 1] + a.z * qs[d + 2] + a.w * qs[d + 3];
            }
            wtil[((size_t)b * HEADS + h) * CDIM + c] = acc;
        }
        __syncthreads();
        if (tid == 0) { __threadfence(); flag_st_rel(FCELL(h, 2), SENT); }
    }

    // ---------------- Gate 1: all 12 fold flags of batch b ----------------
    if (tid == 0) wait_flags(FCELL(0, 2), HEADS, CDIM);
    __syncthreads();

    // ---------------- Phase B: dots + fused x->out copy ----------------
    {
        float* const wt = smem;   // reuse 36 KB
        {
            const float4* s4 = (const float4*)(wtil + (size_t)b * HEADS * CDIM);
            float4* d4 = (float4*)wt;
            for (int i = tid; i < HEADS * CDIM / 4; i += 256) d4[i] = s4[i];
        }
        if (tid < HEADS) db[tid] = dbias[b * HEADS + tid];
        __syncthreads();
        const int wave = tid >> 6, lane = tid & 63;
        for (int it = 0; it < 8; it++) {
            const int j = y * 32 + it * 4 + wave;
            if (j >= NTOK) break;
            const float4* xp = (const float4*)(x + ((size_t)b * NTOK + j) * CDIM);
            float4* op = (float4*)(out + O_X + ((size_t)b * NTOK + j) * CDIM);
            float acc[HEADS];
            #pragma unroll
            for (int h = 0; h < HEADS; h++) acc[h] = 0.f;
            #pragma unroll
            for (int i = 0; i < 3; i++) {
                float4 a = xp[i * 64 + lane];
                op[i * 64 + lane] = a;
                const int cbase = i * 256 + lane * 4;
                #pragma unroll
                for (int h = 0; h < HEADS; h++) {
                    float4 w = *(const float4*)(&wt[h * CDIM + cbase]);
                    acc[h] += a.x * w.x + a.y * w.y + a.z * w.z + a.w * w.w;
                }
            }
            #pragma unroll
            for (int off = 32; off; off >>= 1)
                #pragma unroll
                for (int h = 0; h < HEADS; h++) acc[h] += __shfl_xor(acc[h], off);
            if (lane == 0) {
                #pragma unroll
                for (int h = 0; h < HEADS; h++)
                    dots[((size_t)b * HEADS + h) * NTOK + j] = 0.125f * (acc[h] + db[h]);
            }
        }
        __syncthreads();
        if (tid == 0) { __threadfence(); flag_st_rel(FCELL(y, 1), SENT); }
    }

    // ---------------- Phase C: softmax stats + ca + top-404 (block y==0 per batch) ----
    if (y == 0) {
        if (tid == 0) wait_flags(FCELL(0, 1), JBLK, CDIM);
        __syncthreads();
        float* const dl = smem;   // 6924 floats
        {
            const float4* s4 = (const float4*)(dots + (size_t)b * HEADS * NTOK);
            float4* d4 = (float4*)dl;
            for (int i = tid; i < HEADS * NTOK / 4; i += 256) d4[i] = s4[i];  // 6924 = 4*1731
        }
        __syncthreads();
        {
            const int w = tid >> 6, lane = tid & 63;   // wave w handles heads 3w..3w+2
            #pragma unroll
            for (int hh = 0; hh < 3; hh++) {
                const int h = w * 3 + hh;
                const float* row = dl + h * NTOK;
                float m = -3.4e38f;
                for (int j = lane; j < NTOK; j += 64) m = fmaxf(m, row[j]);
                #pragma unroll
                for (int off = 32; off; off >>= 1) m = fmaxf(m, __shfl_xor(m, off));
                float s = 0.f;
                for (int j = lane; j < NTOK; j += 64) s += expf(row[j] - m);
                #pragma unroll
                for (int off = 32; off; off >>= 1) s += __shfl_xor(s, off);
                if (lane == 0) { mh[h] = m; sh[h] = s; }
            }
        }
        __syncthreads();
        for (int t = tid; t < NPATCH; t += 256) {
            float ca = 0.f;
            #pragma unroll
            for (int h = 0; h < HEADS; h++)
                ca += expf(dl[h * NTOK + 1 + t] - mh[h]) / sh[h];
            ca *= (1.f / 12.f);
            out[O_CA + (size_t)b * NPATCH + t] = ca;
            vals[t] = __float_as_uint(ca);   // ca > 0 -> bit order == value order
        }
        __syncthreads();
        for (int t = tid; t < NPATCH; t += 256) {
            const unsigned myv = vals[t];
            int rank = 0;
            for (int j = 0; j < NPATCH; j++) {
                const unsigned v = vals[j];
                rank += (v > myv) || (v == myv && j < t);   // tie: lower index first
            }
            flags[t] = (rank < FT) ? 1 : 0;
        }
        __syncthreads();
        for (int t = tid; t < NPATCH; t += 256) {
            if (flags[t]) {
                int pos = 0;
                for (int j = 0; j < t; j++) pos += flags[j];
                indws[b * FT + pos] = t;
                out[O_IND + (size_t)b * FT + pos] = (float)t;
            }
        }
        if (b == 0 && tid == 0 && write_ft) out[O_FT] = (float)FT;
        __syncthreads();
        if (tid == 0) {
            __threadfence();
            for (int i = 0; i < JBLK; i++) flag_st_rel(FCELL(i, 0), SENT);
        }
    } else {
        if (tid == 0) wait_flags(FCELL(y, 0), 1, 0);
        __syncthreads();
    }

    // ---------------- Phase D: index broadcast (rows t = y + 19k) ----------------
    // Overwrites every flag cell with its final graded value; the float4 covering
    // a block's own flag cells (row y, f=0) is written by tid 0 after its gates.
    {
        const int K = (FT - 1 - y) / JBLK + 1;
        const int total = K * 192;               // 192 float4 per 768-float row
        for (int f = tid; f < total; f += 256) {
            const int k = f / 192, c = f - k * 192;
            const int t = y + k * JBLK;
            const float v = (float)indws[b * FT + t];
            float4 o; o.x = v; o.y = v; o.z = v; o.w = v;
            ((float4*)(out + O_INDEX + ((size_t)b * FT + t) * CDIM))[c] = o;
        }
    }
    #undef FCELL
}

extern "C" void kernel_launch(void* const* d_in, const int* in_sizes, int n_in,
                              void* d_out, int out_size, void* d_ws, size_t ws_size,
                              hipStream_t stream) {
    const float* x  = (const float*)d_in[0];
    const float* W  = (const float*)d_in[2];   // W_qkv [768, 2304]
    const float* bq = (const float*)d_in[3];   // b_qkv [2304]
    float* ws = (float*)d_ws;
    float* out = (float*)d_out;
    const int write_ft = (out_size > (int)O_FT) ? 1 : 0;
    k_mega<<<dim3(BATCH, JBLK), 256, 0, stream>>>(x, W, bq, ws, out, write_ft);
}

// Round 2
// 279.021 us; speedup vs baseline: 2.2048x; 2.2048x over previous
//
#include <hip/hip_runtime.h>
#include <math.h>

#define BATCH 32
#define NTOK 577
#define NPATCH 576
#define CDIM 768
#define HEADS 12
#define DHEAD 64
#define W3 2304
#define FT 404

// ---- workspace layout (float offsets) ----
#define WS_WTIL  24576      // 32*12*768         -> 319488
#define WS_DBIAS 319488     // 32*12             -> 319872
#define WS_DOTS  319872     // 32*12*577         -> 541440

// ---- output layout (float offsets) ----
#define O_X      0ULL
#define O_INDEX  14180352ULL
#define O_IND    24109056ULL
#define O_CA     24121984ULL
#define O_FT     24140416ULL

// K_fold: grid (12 heads, 8 batch-groups of 4). Per block: q[4][64] for head h,
// dbias, then wtil[4][768]. W read once per block (2x196 KB) -> 38 MB total
// (vs 150 MB for per-(b,h) blocks). q held in registers for phase 2.
__global__ __launch_bounds__(256) void k_fold(const float* __restrict__ x,
                                              const float* __restrict__ W,
                                              const float* __restrict__ bq,
                                              float* __restrict__ wtil,
                                              float* __restrict__ dbias) {
    __shared__ float x0s[4 * CDIM];   // 12 KB
    __shared__ float qs[4 * DHEAD];   // 1 KB
    const int h = blockIdx.x, bg = blockIdx.y, tid = threadIdx.x;
    const int bg4 = bg * 4;
    // stage 4 CLS tokens
    {
        float4* d4 = (float4*)x0s;
        for (int i = tid; i < 4 * CDIM / 4; i += 256) {
            const int bl = i / 192, r = i - bl * 192;
            d4[i] = ((const float4*)(x + (size_t)(bg4 + bl) * NTOK * CDIM))[r];
        }
    }
    __syncthreads();
    // phase 1: q (wave w handles batch w; lane = d). Same Wq line for all 4
    // waves -> L1 broadcast. 768 strided loads, unroll-16 for MLP.
    {
        const int d = tid & 63, wv = tid >> 6;
        const float* Wq = W + h * DHEAD + d;
        const float* xrow = x0s + wv * CDIM;
        float acc = 0.f;
        #pragma unroll 16
        for (int c = 0; c < CDIM; c++) acc += xrow[c] * Wq[(size_t)c * W3];
        const float q = acc + bq[h * DHEAD + d];
        qs[wv * DHEAD + d] = q;
        float t = q * bq[CDIM + h * DHEAD + d];
        #pragma unroll
        for (int off = 32; off; off >>= 1) t += __shfl_down(t, off);
        if (d == 0) dbias[(bg4 + wv) * HEADS + h] = t;
    }
    __syncthreads();
    // phase 2: wtil[b][c] = sum_d q[b][d]*Wk[c][d]; q in 16 float4 registers.
    {
        const int bl = tid >> 6, ci = tid & 63;
        float4 q4[16];
        const float4* qp = (const float4*)(qs + bl * DHEAD);
        #pragma unroll
        for (int t2 = 0; t2 < 16; t2++) q4[t2] = qp[t2];
        float* wout = wtil + ((size_t)(bg4 + bl) * HEADS + h) * CDIM;
        #pragma unroll 2
        for (int k = 0; k < 12; k++) {
            const int c = ci + k * 64;
            const float4* wr = (const float4*)(W + (size_t)c * W3 + CDIM + h * DHEAD);
            float acc = 0.f;
            #pragma unroll
            for (int t2 = 0; t2 < 16; t2++) {
                const float4 ww = wr[t2];
                acc += ww.x * q4[t2].x + ww.y * q4[t2].y + ww.z * q4[t2].z + ww.w * q4[t2].w;
            }
            wout[c] = acc;
        }
    }
}

// K_dots: unchanged from the 227us baseline (near its traffic floor).
__global__ __launch_bounds__(256) void k_dots(const float* __restrict__ x,
                                              const float* __restrict__ wtil,
                                              const float* __restrict__ dbias,
                                              float* __restrict__ dots,
                                              float* __restrict__ out0) {
    __shared__ float wt[HEADS * CDIM];   // 36 KB
    __shared__ float db[HEADS];
    const int b = blockIdx.x, tid = threadIdx.x;
    for (int i = tid; i < HEADS * CDIM; i += 256) wt[i] = wtil[(size_t)b * HEADS * CDIM + i];
    if (tid < HEADS) db[tid] = dbias[b * HEADS + tid];
    __syncthreads();
    const int wave = tid >> 6, lane = tid & 63;
    for (int it = 0; it < 8; it++) {
        const int j = blockIdx.y * 32 + it * 4 + wave;
        if (j >= NTOK) break;
        const float4* xp = reinterpret_cast<const float4*>(x + ((size_t)b * NTOK + j) * CDIM);
        float4* op = reinterpret_cast<float4*>(out0 + ((size_t)b * NTOK + j) * CDIM);
        float acc[HEADS];
        #pragma unroll
        for (int h = 0; h < HEADS; h++) acc[h] = 0.f;
        #pragma unroll
        for (int i = 0; i < 3; i++) {
            float4 a = xp[i * 64 + lane];
            op[i * 64 + lane] = a;
            const int cbase = i * 256 + lane * 4;
            #pragma unroll
            for (int h = 0; h < HEADS; h++) {
                float4 w = *reinterpret_cast<const float4*>(&wt[h * CDIM + cbase]);
                acc[h] += a.x * w.x + a.y * w.y + a.z * w.z + a.w * w.w;
            }
        }
        #pragma unroll
        for (int off = 32; off; off >>= 1)
            #pragma unroll
            for (int h = 0; h < HEADS; h++) acc[h] += __shfl_xor(acc[h], off);
        if (lane == 0) {
            #pragma unroll
            for (int h = 0; h < HEADS; h++)
                dots[((size_t)b * HEADS + h) * NTOK + j] = 0.125f * (acc[h] + db[h]);
        }
    }
}

// K_catbc: fused softmax-stats + ca + top-404 + index broadcast.
// grid (32, 8): all 8 blocks of a batch redundantly compute ca/rank/compaction
// (deterministic), y==0 writes ca/ind/ft, every block writes 1/8 of the
// 39.7 MB index broadcast. No indws round-trip, one node instead of two.
__global__ __launch_bounds__(256) void k_catbc(const float* __restrict__ dots,
                                               float* __restrict__ out,
                                               int write_ft) {
    __shared__ float dl[HEADS * NTOK];        // 27.7 KB
    __shared__ float mh[HEADS], sh[HEADS];
    __shared__ unsigned vals[NPATCH];
    __shared__ unsigned long long segmask[9];
    __shared__ int segoff[9];
    __shared__ int ind_lds[FT];
    const int b = blockIdx.x, y = blockIdx.y, tid = threadIdx.x;
    {
        const float4* s4 = (const float4*)(dots + (size_t)b * HEADS * NTOK);
        float4* d4 = (float4*)dl;
        for (int i = tid; i < HEADS * NTOK / 4; i += 256) d4[i] = s4[i];   // 6924 = 4*1731
    }
    __syncthreads();
    const int w = tid >> 6, lane = tid & 63;
    // softmax stats: wave w handles heads 3w..3w+2
    #pragma unroll
    for (int hh = 0; hh < 3; hh++) {
        const int h = w * 3 + hh;
        const float* row = dl + h * NTOK;
        float m = -3.4e38f;
        for (int j = lane; j < NTOK; j += 64) m = fmaxf(m, row[j]);
        #pragma unroll
        for (int off = 32; off; off >>= 1) m = fmaxf(m, __shfl_xor(m, off));
        float s = 0.f;
        for (int j = lane; j < NTOK; j += 64) s += expf(row[j] - m);
        #pragma unroll
        for (int off = 32; off; off >>= 1) s += __shfl_xor(s, off);
        if (lane == 0) { mh[h] = m; sh[h] = s; }
    }
    __syncthreads();
    for (int t = tid; t < NPATCH; t += 256) {
        float ca = 0.f;
        #pragma unroll
        for (int h = 0; h < HEADS; h++)
            ca += expf(dl[h * NTOK + 1 + t] - mh[h]) / sh[h];
        ca *= (1.f / 12.f);
        if (y == 0) out[O_CA + (size_t)b * NPATCH + t] = ca;
        vals[t] = __float_as_uint(ca);   // ca > 0 -> bit order == value order
    }
    __syncthreads();
    // rank (uint4-vectorized) + ballot -> per-64-segment masks
    {
        const uint4* v4 = (const uint4*)vals;
        for (int s = w; s < 9; s += 4) {
            const int t = s * 64 + lane;
            const unsigned myv = vals[t];
            int rank = 0;
            #pragma unroll 4
            for (int j4 = 0; j4 < NPATCH / 4; j4++) {
                const uint4 vv = v4[j4];
                const int j = j4 * 4;
                rank += (vv.x > myv) || (vv.x == myv && j     < t);
                rank += (vv.y > myv) || (vv.y == myv && j + 1 < t);
                rank += (vv.z > myv) || (vv.z == myv && j + 2 < t);
                rank += (vv.w > myv) || (vv.w == myv && j + 3 < t);
            }
            const unsigned long long mask = __ballot(rank < FT);
            if (lane == 0) segmask[s] = mask;
        }
    }
    __syncthreads();
    if (tid == 0) {
        int acc = 0;
        #pragma unroll
        for (int s = 0; s < 9; s++) { segoff[s] = acc; acc += __popcll(segmask[s]); }
    }
    __syncthreads();
    for (int s = w; s < 9; s += 4) {
        const int t = s * 64 + lane;
        const unsigned long long mask = segmask[s];
        if ((mask >> lane) & 1ull) {
            const int pos = segoff[s] + __popcll(mask & ((1ull << lane) - 1ull));
            ind_lds[pos] = t;
            if (y == 0) out[O_IND + (size_t)b * FT + pos] = (float)t;
        }
    }
    if (y == 0 && b == 0 && tid == 0 && write_ft) out[O_FT] = (float)FT;
    __syncthreads();
    // broadcast: rows r = y, y+8, ... (50-51 rows of 768 floats per block)
    {
        const int nrows = (FT - 1 - y) / 8 + 1;
        const int total = nrows * 192;
        for (int f = tid; f < total; f += 256) {
            const int k = f / 192, cc = f - k * 192;
            const int r = y + k * 8;
            const float v = (float)ind_lds[r];
            float4 o; o.x = v; o.y = v; o.z = v; o.w = v;
            ((float4*)(out + O_INDEX + ((size_t)b * FT + r) * CDIM))[cc] = o;
        }
    }
}

extern "C" void kernel_launch(void* const* d_in, const int* in_sizes, int n_in,
                              void* d_out, int out_size, void* d_ws, size_t ws_size,
                              hipStream_t stream) {
    const float* x  = (const float*)d_in[0];
    const float* W  = (const float*)d_in[2];   // W_qkv [768, 2304]
    const float* bq = (const float*)d_in[3];   // b_qkv [2304]
    float* ws = (float*)d_ws;
    float* out = (float*)d_out;

    k_fold<<<dim3(HEADS, 8), 256, 0, stream>>>(x, W, bq, ws + WS_WTIL, ws + WS_DBIAS);
    k_dots<<<dim3(BATCH, 19), 256, 0, stream>>>(x, ws + WS_WTIL, ws + WS_DBIAS,
                                                ws + WS_DOTS, out + O_X);
    const int write_ft = (out_size > (int)O_FT) ? 1 : 0;
    k_catbc<<<dim3(BATCH, 8), 256, 0, stream>>>(ws + WS_DOTS, out, write_ft);
}

// Round 3
// 246.766 us; speedup vs baseline: 2.4929x; 1.1307x over previous
//
#include <hip/hip_runtime.h>
#include <math.h>

#define BATCH 32
#define NTOK 577
#define NPATCH 576
#define CDIM 768
#define HEADS 12
#define DHEAD 64
#define W3 2304
#define FT 404

// ---- workspace layout (float offsets) ----
#define WS_WTIL  24576      // 32*12*768         -> 319488
#define WS_DBIAS 319488     // 32*12             -> 319872
#define WS_DOTS  319872     // 32*12*577         -> 541440

// ---- output layout (float offsets) ----
#define O_X      0ULL
#define O_INDEX  14180352ULL
#define O_IND    24109056ULL
#define O_CA     24121984ULL
#define O_FT     24140416ULL

// K_fold: grid (32 b, 12 h), 512 threads. 8-way c-split q reduction with 32
// loads in flight per thread -> ~1 us latency exposure; 12 waves/CU.
__global__ __launch_bounds__(512) void k_fold(const float* __restrict__ x,
                                              const float* __restrict__ W,
                                              const float* __restrict__ bq,
                                              float* __restrict__ wtil,
                                              float* __restrict__ dbias) {
    __shared__ float x0s[CDIM];   // 3 KB
    __shared__ float red[512];
    __shared__ float qs[DHEAD];
    const int b = blockIdx.x, h = blockIdx.y, tid = threadIdx.x;
    if (tid < CDIM / 4)
        ((float4*)x0s)[tid] = ((const float4*)(x + (size_t)b * NTOK * CDIM))[tid];
    __syncthreads();
    // phase 1: thread (seg,d), seg in [0,8): partial q over 96 c's
    {
        const int d = tid & 63, seg = tid >> 6;
        const float* Wq = W + h * DHEAD + d;
        const int c0 = seg * 96;
        float acc = 0.f;
        #pragma unroll 32
        for (int c = c0; c < c0 + 96; c++) acc += x0s[c] * Wq[(size_t)c * W3];
        red[tid] = acc;
    }
    __syncthreads();
    if (tid < DHEAD) {
        float q = red[tid];
        #pragma unroll
        for (int s = 1; s < 8; s++) q += red[tid + s * 64];
        q += bq[h * DHEAD + tid];
        qs[tid] = q;
        float t = q * bq[CDIM + h * DHEAD + tid];
        #pragma unroll
        for (int off = 32; off; off >>= 1) t += __shfl_down(t, off);
        if (tid == 0) dbias[b * HEADS + h] = t;
    }
    __syncthreads();
    // phase 2: wtil[c] = sum_d qs[d] * Wk[c][d]
    for (int c = tid; c < CDIM; c += 512) {
        const float* wr = W + (size_t)c * W3 + CDIM + h * DHEAD;
        float acc = 0.f;
        #pragma unroll
        for (int d = 0; d < DHEAD; d += 4) {
            float4 a = *reinterpret_cast<const float4*>(wr + d);
            acc += a.x * qs[d] + a.y * qs[d + 1] + a.z * qs[d + 2] + a.w * qs[d + 3];
        }
        wtil[((size_t)b * HEADS + h) * CDIM + c] = acc;
    }
}

// K_dots: grid (32 b, 19), 256 threads, NO LDS. Wave w owns heads 3w..3w+2;
// wt fragment (9 float4) held in registers; inner loop = x load + FMA + shfl.
// Per-lane accumulation order and shfl_xor sequence identical to the
// verified version (bit-exact dots).
__global__ __launch_bounds__(256) void k_dots(const float* __restrict__ x,
                                              const float* __restrict__ wtil,
                                              const float* __restrict__ dbias,
                                              float* __restrict__ dots,
                                              float* __restrict__ out0) {
    const int b = blockIdx.x, tid = threadIdx.x;
    const int w = tid >> 6, lane = tid & 63, h0 = w * 3;
    float4 wr[3][3];
    float db[3];
    #pragma unroll
    for (int hh = 0; hh < 3; hh++) {
        #pragma unroll
        for (int i = 0; i < 3; i++)
            wr[hh][i] = *reinterpret_cast<const float4*>(
                wtil + ((size_t)b * HEADS + h0 + hh) * CDIM + i * 256 + lane * 4);
        db[hh] = dbias[b * HEADS + h0 + hh];
    }
    const int jbase = blockIdx.y * 32;
    for (int jj = 0; jj < 32; jj++) {
        const int j = jbase + jj;
        if (j >= NTOK) break;
        const float4* xp = reinterpret_cast<const float4*>(x + ((size_t)b * NTOK + j) * CDIM);
        const float4 a0 = xp[lane], a1 = xp[64 + lane], a2 = xp[128 + lane];
        if (w == 0) {
            float4* op = reinterpret_cast<float4*>(out0 + ((size_t)b * NTOK + j) * CDIM);
            op[lane] = a0; op[64 + lane] = a1; op[128 + lane] = a2;
        }
        float acc[3];
        #pragma unroll
        for (int hh = 0; hh < 3; hh++) acc[hh] = 0.f;
        #pragma unroll
        for (int hh = 0; hh < 3; hh++)
            acc[hh] += a0.x * wr[hh][0].x + a0.y * wr[hh][0].y
                     + a0.z * wr[hh][0].z + a0.w * wr[hh][0].w;
        #pragma unroll
        for (int hh = 0; hh < 3; hh++)
            acc[hh] += a1.x * wr[hh][1].x + a1.y * wr[hh][1].y
                     + a1.z * wr[hh][1].z + a1.w * wr[hh][1].w;
        #pragma unroll
        for (int hh = 0; hh < 3; hh++)
            acc[hh] += a2.x * wr[hh][2].x + a2.y * wr[hh][2].y
                     + a2.z * wr[hh][2].z + a2.w * wr[hh][2].w;
        #pragma unroll
        for (int off = 32; off; off >>= 1)
            #pragma unroll
            for (int hh = 0; hh < 3; hh++) acc[hh] += __shfl_xor(acc[hh], off);
        if (lane == 0) {
            #pragma unroll
            for (int hh = 0; hh < 3; hh++)
                dots[((size_t)b * HEADS + h0 + hh) * NTOK + j] = 0.125f * (acc[hh] + db[hh]);
        }
    }
}

// K_catbc: grid (32 b, 16), 512 threads. Redundant softmax/rank per block
// (parallel), y==0 writes ca/ind/ft, all blocks write 1/16 of the broadcast.
__global__ __launch_bounds__(512) void k_catbc(const float* __restrict__ dots,
                                               float* __restrict__ out,
                                               int write_ft) {
    __shared__ float dl[HEADS * NTOK];        // 27.7 KB
    __shared__ float mh[HEADS], sh[HEADS];
    __shared__ unsigned vals[NPATCH];
    __shared__ unsigned long long segmask[9];
    __shared__ int segoff[9];
    __shared__ int ind_lds[FT];
    const int b = blockIdx.x, y = blockIdx.y, tid = threadIdx.x;
    {
        const float4* s4 = (const float4*)(dots + (size_t)b * HEADS * NTOK);
        float4* d4 = (float4*)dl;
        for (int i = tid; i < HEADS * NTOK / 4; i += 512) d4[i] = s4[i];   // 1731 float4
    }
    __syncthreads();
    const int w = tid >> 6, lane = tid & 63;
    for (int h = w; h < HEADS; h += 8) {
        const float* row = dl + h * NTOK;
        float m = -3.4e38f;
        for (int j = lane; j < NTOK; j += 64) m = fmaxf(m, row[j]);
        #pragma unroll
        for (int off = 32; off; off >>= 1) m = fmaxf(m, __shfl_xor(m, off));
        float s = 0.f;
        for (int j = lane; j < NTOK; j += 64) s += expf(row[j] - m);
        #pragma unroll
        for (int off = 32; off; off >>= 1) s += __shfl_xor(s, off);
        if (lane == 0) { mh[h] = m; sh[h] = s; }
    }
    __syncthreads();
    for (int t = tid; t < NPATCH; t += 512) {
        float ca = 0.f;
        #pragma unroll
        for (int h = 0; h < HEADS; h++)
            ca += expf(dl[h * NTOK + 1 + t] - mh[h]) / sh[h];
        ca *= (1.f / 12.f);
        if (y == 0) out[O_CA + (size_t)b * NPATCH + t] = ca;
        vals[t] = __float_as_uint(ca);   // ca > 0 -> bit order == value order
    }
    __syncthreads();
    {
        const uint4* v4 = (const uint4*)vals;
        for (int s = w; s < 9; s += 8) {
            const int t = s * 64 + lane;
            const unsigned myv = vals[t];
            int rank = 0;
            #pragma unroll 8
            for (int j4 = 0; j4 < NPATCH / 4; j4++) {
                const uint4 vv = v4[j4];
                const int j = j4 * 4;
                rank += (vv.x > myv) || (vv.x == myv && j     < t);
                rank += (vv.y > myv) || (vv.y == myv && j + 1 < t);
                rank += (vv.z > myv) || (vv.z == myv && j + 2 < t);
                rank += (vv.w > myv) || (vv.w == myv && j + 3 < t);
            }
            const unsigned long long mask = __ballot(rank < FT);
            if (lane == 0) segmask[s] = mask;
        }
    }
    __syncthreads();
    if (tid == 0) {
        int acc = 0;
        #pragma unroll
        for (int s = 0; s < 9; s++) { segoff[s] = acc; acc += __popcll(segmask[s]); }
    }
    __syncthreads();
    for (int s = w; s < 9; s += 8) {
        const int t = s * 64 + lane;
        const unsigned long long mask = segmask[s];
        if ((mask >> lane) & 1ull) {
            const int pos = segoff[s] + __popcll(mask & ((1ull << lane) - 1ull));
            ind_lds[pos] = t;
            if (y == 0) out[O_IND + (size_t)b * FT + pos] = (float)t;
        }
    }
    if (y == 0 && b == 0 && tid == 0 && write_ft) out[O_FT] = (float)FT;
    __syncthreads();
    // broadcast: rows r = y + 16k (25-26 rows of 192 float4 per block)
    {
        const int nrows = (FT - 1 - y) / 16 + 1;
        const int total = nrows * 192;
        for (int f = tid; f < total; f += 512) {
            const int k = f / 192, cc = f - k * 192;
            const int r = y + k * 16;
            const float v = (float)ind_lds[r];
            float4 o; o.x = v; o.y = v; o.z = v; o.w = v;
            ((float4*)(out + O_INDEX + ((size_t)b * FT + r) * CDIM))[cc] = o;
        }
    }
}

extern "C" void kernel_launch(void* const* d_in, const int* in_sizes, int n_in,
                              void* d_out, int out_size, void* d_ws, size_t ws_size,
                              hipStream_t stream) {
    const float* x  = (const float*)d_in[0];
    const float* W  = (const float*)d_in[2];   // W_qkv [768, 2304]
    const float* bq = (const float*)d_in[3];   // b_qkv [2304]
    float* ws = (float*)d_ws;
    float* out = (float*)d_out;

    k_fold<<<dim3(BATCH, HEADS), 512, 0, stream>>>(x, W, bq, ws + WS_WTIL, ws + WS_DBIAS);
    k_dots<<<dim3(BATCH, 19), 256, 0, stream>>>(x, ws + WS_WTIL, ws + WS_DBIAS,
                                                ws + WS_DOTS, out + O_X);
    const int write_ft = (out_size > (int)O_FT) ? 1 : 0;
    k_catbc<<<dim3(BATCH, 16), 512, 0, stream>>>(ws + WS_DOTS, out, write_ft);
}

// Round 4
// 234.020 us; speedup vs baseline: 2.6287x; 1.0545x over previous
//
#include <hip/hip_runtime.h>
#include <math.h>

#define BATCH 32
#define NTOK 577
#define NPATCH 576
#define CDIM 768
#define HEADS 12
#define DHEAD 64
#define W3 2304
#define FT 404

// ---- workspace layout (float offsets) ----
#define WS_WTIL  24576      // 32*12*768         -> 319488
#define WS_DBIAS 319488     // 32*12             -> 319872
#define WS_DOTS  319872     // 32*12*577         -> 541440

// ---- output layout (float offsets) ----
#define O_X      0ULL
#define O_INDEX  14180352ULL
#define O_IND    24109056ULL
#define O_CA     24121984ULL
#define O_FT     24140416ULL

// K_fold: unchanged from round 3 (awaiting counters before restructure).
__global__ __launch_bounds__(512) void k_fold(const float* __restrict__ x,
                                              const float* __restrict__ W,
                                              const float* __restrict__ bq,
                                              float* __restrict__ wtil,
                                              float* __restrict__ dbias) {
    __shared__ float x0s[CDIM];   // 3 KB
    __shared__ float red[512];
    __shared__ float qs[DHEAD];
    const int b = blockIdx.x, h = blockIdx.y, tid = threadIdx.x;
    if (tid < CDIM / 4)
        ((float4*)x0s)[tid] = ((const float4*)(x + (size_t)b * NTOK * CDIM))[tid];
    __syncthreads();
    {
        const int d = tid & 63, seg = tid >> 6;
        const float* Wq = W + h * DHEAD + d;
        const int c0 = seg * 96;
        float acc = 0.f;
        #pragma unroll 32
        for (int c = c0; c < c0 + 96; c++) acc += x0s[c] * Wq[(size_t)c * W3];
        red[tid] = acc;
    }
    __syncthreads();
    if (tid < DHEAD) {
        float q = red[tid];
        #pragma unroll
        for (int s = 1; s < 8; s++) q += red[tid + s * 64];
        q += bq[h * DHEAD + tid];
        qs[tid] = q;
        float t = q * bq[CDIM + h * DHEAD + tid];
        #pragma unroll
        for (int off = 32; off; off >>= 1) t += __shfl_down(t, off);
        if (tid == 0) dbias[b * HEADS + h] = t;
    }
    __syncthreads();
    for (int c = tid; c < CDIM; c += 512) {
        const float* wr = W + (size_t)c * W3 + CDIM + h * DHEAD;
        float acc = 0.f;
        #pragma unroll
        for (int d = 0; d < DHEAD; d += 4) {
            float4 a = *reinterpret_cast<const float4*>(wr + d);
            acc += a.x * qs[d] + a.y * qs[d + 1] + a.z * qs[d + 2] + a.w * qs[d + 3];
        }
        wtil[((size_t)b * HEADS + h) * CDIM + c] = acc;
    }
}

// K_dots v3: grid (32 b, 37), 256 thr, 16 j per block in 4-row groups with
// explicit 2-deep register double-buffering (load group g+1 while computing g).
// Wave u stores the out0 copy of row u of each group (all waves hold the row).
// Accumulation order and shfl butterfly bit-identical to verified version.
#define LOADG(A, G)                                                               \
    {                                                                             \
        _Pragma("unroll")                                                         \
        for (int u = 0; u < 4; u++) {                                             \
            const int j = jbase + (G) * 4 + u;                                    \
            if (j < NTOK) {                                                       \
                const float4* xp =                                                \
                    (const float4*)(x + ((size_t)b * NTOK + j) * CDIM);           \
                A[u][0] = xp[lane]; A[u][1] = xp[64 + lane]; A[u][2] = xp[128 + lane]; \
            } else {                                                              \
                A[u][0] = A[u][1] = A[u][2] = make_float4(0.f, 0.f, 0.f, 0.f);    \
            }                                                                     \
        }                                                                         \
    }

#define COMPG(A, G)                                                               \
    {                                                                             \
        _Pragma("unroll")                                                         \
        for (int u = 0; u < 4; u++) {                                             \
            const int j = jbase + (G) * 4 + u;                                    \
            if (w == u && j < NTOK) {                                             \
                float4* op = (float4*)(out0 + ((size_t)b * NTOK + j) * CDIM);     \
                op[lane] = A[u][0]; op[64 + lane] = A[u][1]; op[128 + lane] = A[u][2]; \
            }                                                                     \
        }                                                                         \
        float acc[4][3];                                                          \
        _Pragma("unroll")                                                         \
        for (int u = 0; u < 4; u++) { acc[u][0] = acc[u][1] = acc[u][2] = 0.f; }  \
        _Pragma("unroll")                                                         \
        for (int i = 0; i < 3; i++)                                               \
            _Pragma("unroll")                                                     \
            for (int u = 0; u < 4; u++)                                           \
                _Pragma("unroll")                                                 \
                for (int hh = 0; hh < 3; hh++)                                    \
                    acc[u][hh] += A[u][i].x * wr[hh][i].x + A[u][i].y * wr[hh][i].y \
                                + A[u][i].z * wr[hh][i].z + A[u][i].w * wr[hh][i].w; \
        _Pragma("unroll")                                                         \
        for (int off = 32; off; off >>= 1)                                        \
            _Pragma("unroll")                                                     \
            for (int u = 0; u < 4; u++)                                           \
                _Pragma("unroll")                                                 \
                for (int hh = 0; hh < 3; hh++)                                    \
                    acc[u][hh] += __shfl_xor(acc[u][hh], off);                    \
        if (lane == 0) {                                                          \
            _Pragma("unroll")                                                     \
            for (int u = 0; u < 4; u++) {                                         \
                const int j = jbase + (G) * 4 + u;                                \
                if (j < NTOK) {                                                   \
                    _Pragma("unroll")                                             \
                    for (int hh = 0; hh < 3; hh++)                                \
                        dots[((size_t)b * HEADS + h0 + hh) * NTOK + j] =          \
                            0.125f * (acc[u][hh] + db[hh]);                       \
                }                                                                 \
            }                                                                     \
        }                                                                         \
    }

__global__ __launch_bounds__(256, 3) void k_dots(const float* __restrict__ x,
                                                 const float* __restrict__ wtil,
                                                 const float* __restrict__ dbias,
                                                 float* __restrict__ dots,
                                                 float* __restrict__ out0) {
    const int b = blockIdx.x, tid = threadIdx.x;
    const int w = tid >> 6, lane = tid & 63, h0 = w * 3;
    float4 wr[3][3];
    float db[3];
    #pragma unroll
    for (int hh = 0; hh < 3; hh++) {
        #pragma unroll
        for (int i = 0; i < 3; i++)
            wr[hh][i] = *reinterpret_cast<const float4*>(
                wtil + ((size_t)b * HEADS + h0 + hh) * CDIM + i * 256 + lane * 4);
        db[hh] = dbias[b * HEADS + h0 + hh];
    }
    const int jbase = blockIdx.y * 16;
    float4 abuf[4][3], nbuf[4][3];
    LOADG(abuf, 0);
    LOADG(nbuf, 1);
    COMPG(abuf, 0);
    LOADG(abuf, 2);
    COMPG(nbuf, 1);
    LOADG(nbuf, 3);
    COMPG(abuf, 2);
    COMPG(nbuf, 3);
}

// K_catbc: unchanged from round 3 (awaiting counters before restructure).
__global__ __launch_bounds__(512) void k_catbc(const float* __restrict__ dots,
                                               float* __restrict__ out,
                                               int write_ft) {
    __shared__ float dl[HEADS * NTOK];        // 27.7 KB
    __shared__ float mh[HEADS], sh[HEADS];
    __shared__ unsigned vals[NPATCH];
    __shared__ unsigned long long segmask[9];
    __shared__ int segoff[9];
    __shared__ int ind_lds[FT];
    const int b = blockIdx.x, y = blockIdx.y, tid = threadIdx.x;
    {
        const float4* s4 = (const float4*)(dots + (size_t)b * HEADS * NTOK);
        float4* d4 = (float4*)dl;
        for (int i = tid; i < HEADS * NTOK / 4; i += 512) d4[i] = s4[i];   // 1731 float4
    }
    __syncthreads();
    const int w = tid >> 6, lane = tid & 63;
    for (int h = w; h < HEADS; h += 8) {
        const float* row = dl + h * NTOK;
        float m = -3.4e38f;
        for (int j = lane; j < NTOK; j += 64) m = fmaxf(m, row[j]);
        #pragma unroll
        for (int off = 32; off; off >>= 1) m = fmaxf(m, __shfl_xor(m, off));
        float s = 0.f;
        for (int j = lane; j < NTOK; j += 64) s += expf(row[j] - m);
        #pragma unroll
        for (int off = 32; off; off >>= 1) s += __shfl_xor(s, off);
        if (lane == 0) { mh[h] = m; sh[h] = s; }
    }
    __syncthreads();
    for (int t = tid; t < NPATCH; t += 512) {
        float ca = 0.f;
        #pragma unroll
        for (int h = 0; h < HEADS; h++)
            ca += expf(dl[h * NTOK + 1 + t] - mh[h]) / sh[h];
        ca *= (1.f / 12.f);
        if (y == 0) out[O_CA + (size_t)b * NPATCH + t] = ca;
        vals[t] = __float_as_uint(ca);   // ca > 0 -> bit order == value order
    }
    __syncthreads();
    {
        const uint4* v4 = (const uint4*)vals;
        for (int s = w; s < 9; s += 8) {
            const int t = s * 64 + lane;
            const unsigned myv = vals[t];
            int rank = 0;
            #pragma unroll 8
            for (int j4 = 0; j4 < NPATCH / 4; j4++) {
                const uint4 vv = v4[j4];
                const int j = j4 * 4;
                rank += (vv.x > myv) || (vv.x == myv && j     < t);
                rank += (vv.y > myv) || (vv.y == myv && j + 1 < t);
                rank += (vv.z > myv) || (vv.z == myv && j + 2 < t);
                rank += (vv.w > myv) || (vv.w == myv && j + 3 < t);
            }
            const unsigned long long mask = __ballot(rank < FT);
            if (lane == 0) segmask[s] = mask;
        }
    }
    __syncthreads();
    if (tid == 0) {
        int acc = 0;
        #pragma unroll
        for (int s = 0; s < 9; s++) { segoff[s] = acc; acc += __popcll(segmask[s]); }
    }
    __syncthreads();
    for (int s = w; s < 9; s += 8) {
        const int t = s * 64 + lane;
        const unsigned long long mask = segmask[s];
        if ((mask >> lane) & 1ull) {
            const int pos = segoff[s] + __popcll(mask & ((1ull << lane) - 1ull));
            ind_lds[pos] = t;
            if (y == 0) out[O_IND + (size_t)b * FT + pos] = (float)t;
        }
    }
    if (y == 0 && b == 0 && tid == 0 && write_ft) out[O_FT] = (float)FT;
    __syncthreads();
    {
        const int nrows = (FT - 1 - y) / 16 + 1;
        const int total = nrows * 192;
        for (int f = tid; f < total; f += 512) {
            const int k = f / 192, cc = f - k * 192;
            const int r = y + k * 16;
            const float v = (float)ind_lds[r];
            float4 o; o.x = v; o.y = v; o.z = v; o.w = v;
            ((float4*)(out + O_INDEX + ((size_t)b * FT + r) * CDIM))[cc] = o;
        }
    }
}

extern "C" void kernel_launch(void* const* d_in, const int* in_sizes, int n_in,
                              void* d_out, int out_size, void* d_ws, size_t ws_size,
                              hipStream_t stream) {
    const float* x  = (const float*)d_in[0];
    const float* W  = (const float*)d_in[2];   // W_qkv [768, 2304]
    const float* bq = (const float*)d_in[3];   // b_qkv [2304]
    float* ws = (float*)d_ws;
    float* out = (float*)d_out;

    k_fold<<<dim3(BATCH, HEADS), 512, 0, stream>>>(x, W, bq, ws + WS_WTIL, ws + WS_DBIAS);
    k_dots<<<dim3(BATCH, 37), 256, 0, stream>>>(x, ws + WS_WTIL, ws + WS_DBIAS,
                                                ws + WS_DOTS, out + O_X);
    const int write_ft = (out_size > (int)O_FT) ? 1 : 0;
    k_catbc<<<dim3(BATCH, 16), 512, 0, stream>>>(ws + WS_DOTS, out, write_ft);
}